// Round 12
// baseline (617.059 us; speedup 1.0000x reference)
//
#include <hip/hip_runtime.h>
#include <hip/hip_bf16.h>
#include <hip/hip_cooperative_groups.h>
#include <cstddef>
#include <cstdint>

namespace cg = cooperative_groups;

// Problem constants (fixed by reference)
#define BATCH   2
#define S_LEN   2048
#define D_MODEL 1024
#define NH      16
#define HD      64
#define MAXD    1024

// logits = scores*(1/sqrt(64)) + (scores + rel_bias)*64^-0.25
//        = scores*0.47855339 + rel_bias*0.35355339
#define SCORE_SCALE 0.47855339059327373f
#define BIAS_SCALE  0.35355339059327373f
#define FIXM 8.0f
#define LOG2E 1.4426950408889634f

typedef __attribute__((ext_vector_type(8))) short bf16x8;
typedef __attribute__((ext_vector_type(4))) short bf16x4;
typedef __attribute__((ext_vector_type(4))) float f32x4;

#if __has_builtin(__builtin_amdgcn_mfma_f32_16x16x16bf16_1k)
#define USE_1K 1
#define ARENA_BYTES 16384
#else
#define USE_1K 0
#define ARENA_BYTES 24576
#endif

static __device__ __forceinline__ unsigned short f2bf(float f) {
    __hip_bfloat16 h = __float2bfloat16(f);
    return *reinterpret_cast<unsigned short*>(&h);
}

static __device__ __forceinline__ unsigned int pk_bf16(float lo, float hi) {
#if __has_builtin(__builtin_amdgcn_cvt_pk_bf16_f32)
    auto v = __builtin_amdgcn_cvt_pk_bf16_f32(lo, hi);
    unsigned int r;
    __builtin_memcpy(&r, &v, 4);
    return r;
#else
    __hip_bfloat162 h = __float22bfloat162_rn(make_float2(lo, hi));
    return *reinterpret_cast<unsigned int*>(&h);
#endif
}

#define GLDS(gp, lp) __builtin_amdgcn_global_load_lds( \
    (const __attribute__((address_space(1))) void*)(gp), \
    (__attribute__((address_space(3))) void*)(lp), 16, 0, 0)

// ---------------------------------------------------------------------------
// Phase 0 body: (a) x fp32->bf16, (b) 4 weight transpose+converts,
// (c) per-head bias table pb_t[h][rel+2047] (clamp/scales/log2e folded).
// vblocks: [0,2048) cvt, [2048,6144) wt, [6144,6208) bias.
// ---------------------------------------------------------------------------
static __device__ __forceinline__ void prep_body(
    int bx, int tid, unsigned char* smem,
    const float* __restrict__ x,
    const float* __restrict__ Wq, const float* __restrict__ Wk,
    const float* __restrict__ Wv, const float* __restrict__ Wo,
    const float* __restrict__ pos_bias,
    unsigned short* __restrict__ xb, unsigned short* __restrict__ Wqkvt,
    unsigned short* __restrict__ Wot, float* __restrict__ pb_t)
{
    float (*t)[33] = (float(*)[33])smem;

    if (bx < 2048) {                       // ---- x convert
        const size_t i = ((size_t)bx * 256 + tid) * 8;
        const float4 a = *(const float4*)(x + i);
        const float4 b = *(const float4*)(x + i + 4);
        uint4 u;
        u.x = pk_bf16(a.x, a.y);
        u.y = pk_bf16(a.z, a.w);
        u.z = pk_bf16(b.x, b.y);
        u.w = pk_bf16(b.z, b.w);
        *(uint4*)(xb + i) = u;
    } else if (bx < 6144) {                // ---- weight transpose+convert
        const int bx2 = bx - 2048;
        const int z = bx2 >> 10, inner = bx2 & 1023;
        const int gx = inner & 31, gy = inner >> 5;
        const float* W = (z == 0) ? Wq : (z == 1) ? Wk : (z == 2) ? Wv : Wo;
        unsigned short* hi = (z < 3) ? Wqkvt + (size_t)z * 1024 * 1024 : Wot;
        const int bxx = gx * 32, byy = gy * 32;
        const int tx = tid & 31, ty = tid >> 5;
        #pragma unroll
        for (int i = 0; i < 4; i++)
            t[ty + 8 * i][tx] = W[(size_t)(byy + ty + 8 * i) * 1024 + bxx + tx];
        __syncthreads();
        #pragma unroll
        for (int i = 0; i < 4; i++) {
            const float v = t[tx][ty + 8 * i];
            const size_t o = (size_t)(bxx + ty + 8 * i) * 1024 + byy + tx;
            hi[o] = f2bf(v);
        }
        __syncthreads();   // smem reused by next vblock iteration
    } else {                               // ---- bias table, 16 heads x 4096
        const int o0 = (bx - 6144) * 1024 + tid * 4;
        float v[4];
        #pragma unroll
        for (int j = 0; j < 4; j++) {
            const int o = o0 + j;
            const int hh = o >> 12, ii = o & 4095;
            int rel = ii - 2047;
            rel = min(max(rel, -(MAXD - 1)), MAXD - 1);
            v[j] = (BIAS_SCALE * pos_bias[(size_t)(rel + MAXD - 1) * NH + hh] - FIXM) * LOG2E;
        }
        *(float4*)&pb_t[o0] = *(const float4*)v;
    }
}

// ---------------------------------------------------------------------------
// Phase 1 body: fused QKV GEMM C[4096,3072] = xb @ Wqkvt^T. 128x128, BK=32.
// Col region 0->Q [B,S,D] (+bq), 1->K [B,S,D], 2->V^T [B,H,HD,S] (+bv).
// ---------------------------------------------------------------------------
#define GBK 32

static __device__ __forceinline__ void qkv_body(
    int bnIdx, int bmIdx, int tid, unsigned char* smem,
    const unsigned short* __restrict__ A, const unsigned short* __restrict__ Bt,
    const float* __restrict__ bq, const float* __restrict__ bv,
    unsigned short* __restrict__ Cout)
{
    const int K = 1024;
    unsigned short (*As)[GBK] = (unsigned short(*)[GBK])smem;            // [128][32]
    unsigned short (*Bs)[GBK] = (unsigned short(*)[GBK])(smem + 8192);   // [128][32]

    const int wave = tid >> 6, lane = tid & 63;
    const int quad = lane >> 4, cl = lane & 15;
    const int wm = (wave & 1) * 64, wn = (wave >> 1) * 64;
    const int bm = bmIdx * 128, bn = bnIdx * 128;

    const int sr = wave * 32 + (lane >> 2);
    const int sc = (lane & 3) * 8;
    const unsigned short* aS0 = A  + (size_t)(bm + sr) * K + sc;
    const unsigned short* aS1 = aS0 + (size_t)16 * K;
    const unsigned short* bS0 = Bt + (size_t)(bn + sr) * K + sc;
    const unsigned short* bS1 = bS0 + (size_t)16 * K;
    unsigned short* aD0 = &As[wave * 32][0];
    unsigned short* aD1 = &As[wave * 32 + 16][0];
    unsigned short* bD0 = &Bs[wave * 32][0];
    unsigned short* bD1 = &Bs[wave * 32 + 16][0];

    f32x4 acc[4][4];
    #pragma unroll
    for (int mi = 0; mi < 4; mi++)
        #pragma unroll
        for (int ni = 0; ni < 4; ni++)
            #pragma unroll
            for (int r = 0; r < 4; r++) acc[mi][ni][r] = 0.f;

    for (int k0 = 0; k0 < K; k0 += GBK) {
        __syncthreads();
        GLDS(aS0, aD0); GLDS(aS1, aD1);
        GLDS(bS0, bD0); GLDS(bS1, bD1);
        aS0 += GBK; aS1 += GBK; bS0 += GBK; bS1 += GBK;
        __syncthreads();

        bf16x8 af[4], bf[4];
        #pragma unroll
        for (int mi = 0; mi < 4; mi++)
            af[mi] = *(const bf16x8*)&As[wm + mi * 16 + cl][quad * 8];
        #pragma unroll
        for (int ni = 0; ni < 4; ni++)
            bf[ni] = *(const bf16x8*)&Bs[wn + ni * 16 + cl][quad * 8];
        #pragma unroll
        for (int mi = 0; mi < 4; mi++)
            #pragma unroll
            for (int ni = 0; ni < 4; ni++)
                acc[mi][ni] = __builtin_amdgcn_mfma_f32_16x16x32_bf16(
                    af[mi], bf[ni], acc[mi][ni], 0, 0, 0);
    }
    __syncthreads();   // LDS idle before caller reuses arena

    #pragma unroll
    for (int ni = 0; ni < 4; ni++) {
        const int coln = bn + wn + ni * 16 + cl;
        const int region = coln >> 10, c = coln & 1023;
        const float bs = (region == 0) ? bq[c] : (region == 2) ? bv[c] : 0.f;
        #pragma unroll
        for (int mi = 0; mi < 4; mi++) {
            const int row0 = bm + wm + mi * 16 + quad * 4;
            if (region == 2) {
                const int hh = c >> 6, d = c & 63;
                const int bb = row0 >> 11, s0 = row0 & 2047;
                uint2 w;
                w.x = pk_bf16(acc[mi][ni][0] + bs, acc[mi][ni][1] + bs);
                w.y = pk_bf16(acc[mi][ni][2] + bs, acc[mi][ni][3] + bs);
                unsigned short* dst = Cout + (size_t)8 * 1024 * 1024
                    + (((size_t)bb * NH + hh) * HD + d) * S_LEN + s0;
                *(uint2*)dst = w;
            } else {
                unsigned short* dst = Cout + (size_t)region * 4 * 1024 * 1024;
                #pragma unroll
                for (int r = 0; r < 4; r++)
                    dst[(size_t)(row0 + r) * 1024 + c] = f2bf(acc[mi][ni][r] + bs);
            }
        }
    }
}

// ---------------------------------------------------------------------------
// Phase 2 body: MFMA flash attention (R10 structure, proven race-free):
// TQB=64, single-buffer GLDS staging, m97 2-barrier pattern, XOR-swizzled
// unpadded LDS, register-resident P via mfma_16x16x16 PV, lsum via ones-A MFMA.
// ---------------------------------------------------------------------------
#define TQB 64
#define TKB 64

static __device__ __forceinline__ void attn_body(
    int qt, int h, int b, int tid, unsigned char* smem,
    const unsigned short* __restrict__ Q, const unsigned short* __restrict__ K,
    const unsigned short* __restrict__ VT, const float* __restrict__ pb_t,
    unsigned short* __restrict__ O)
{
    const int wave = tid >> 6, lane = tid & 63;
    const int quad = lane >> 4, col = lane & 15;
    const int qbase = qt * TQB;
    const int qw = qbase + wave * 16;

    unsigned short (*Ks)[HD]  = (unsigned short(*)[HD])smem;             // [64][64]
    unsigned short (*Vs)[TKB] = (unsigned short(*)[TKB])(smem + 8192);   // [64][64]
#if !USE_1K
    unsigned short (*Ps)[TKB] = (unsigned short(*)[TKB])(smem + 16384);  // [4*16][64]
#endif

    bf16x8 qf[2];
    {
        const unsigned short* qp =
            &Q[((size_t)(b * S_LEN) + qw + col) * D_MODEL + h * HD + quad * 8];
        qf[0] = *(const bf16x8*)qp;
        qf[1] = *(const bf16x8*)(qp + 32);
    }

    f32x4 accO[4];
    #pragma unroll
    for (int nb = 0; nb < 4; nb++)
        #pragma unroll
        for (int r = 0; r < 4; r++) accO[nb][r] = 0.f;
#if USE_1K
    f32x4 accL;
    #pragma unroll
    for (int r = 0; r < 4; r++) accL[r] = 0.f;
    const bf16x4 vone = {(short)16256, (short)16256, (short)16256, (short)16256}; // bf16 1.0
#else
    float lsum = 0.f;
#endif

    // GLDS staging: slot s=i*256+tid holds (row=s>>3, chunk (s&7)^(row&7)).
    const int s0 = tid, s1 = 256 + tid;
    const int kr0 = s0 >> 3, kj0 = (s0 & 7) ^ (kr0 & 7);
    const int kr1 = s1 >> 3, kj1 = (s1 & 7) ^ (kr1 & 7);
    const unsigned short* kS0 = K + ((size_t)(b * S_LEN) + kr0) * D_MODEL + h * HD + kj0 * 8;
    const unsigned short* kS1 = K + ((size_t)(b * S_LEN) + kr1) * D_MODEL + h * HD + kj1 * 8;
    const size_t vbase = ((size_t)(b * NH + h) * HD) * S_LEN;
    const unsigned short* vS0 = VT + vbase + (size_t)kr0 * S_LEN + kj0 * 8;
    const unsigned short* vS1 = VT + vbase + (size_t)kr1 * S_LEN + kj1 * 8;
    unsigned short* kD = &Ks[0][0] + wave * 512;   // wave-uniform LDS bases
    unsigned short* vD = &Vs[0][0] + wave * 512;

    const float* pbh = pb_t + h * 4096;
    const float* pb_lane = pbh + (qbase + wave * 16 + col - quad * 4 + 2047);
    const float SC2 = SCORE_SCALE * LOG2E;
    const int jsw = col & 7;   // swizzle key for this lane's rows

    for (int kb = 0; kb < S_LEN; kb += TKB) {
        __syncthreads();   // prior tile's LDS reads complete before overwrite
        GLDS(kS0, kD); GLDS(kS1, kD + 2048);
        GLDS(vS0, vD); GLDS(vS1, vD + 2048);
        kS0 += (size_t)TKB * D_MODEL; kS1 += (size_t)TKB * D_MODEL;
        vS0 += TKB; vS1 += TKB;

        // bias loads overlap the GLDS drain (global, off the LDS pipe)
        float bias_r[16];
        #pragma unroll
        for (int nb = 0; nb < 4; nb++)
            #pragma unroll
            for (int r = 0; r < 4; r++)
                bias_r[nb * 4 + r] = pb_lane[-(nb * 16 + r)];

        __syncthreads();   // barrier drains vmcnt -> glds data visible

        // QK^T: C[key=nb*16+quad*4+r][q=col]
        f32x4 accS[4];
        #pragma unroll
        for (int nb = 0; nb < 4; nb++)
            #pragma unroll
            for (int r = 0; r < 4; r++) accS[nb][r] = 0.f;
        #pragma unroll
        for (int kk = 0; kk < 2; kk++)
            #pragma unroll
            for (int nb = 0; nb < 4; nb++) {
                const bf16x8 kf = *(const bf16x8*)
                    &Ks[nb * 16 + col][((kk * 4 + quad) ^ jsw) * 8];
                accS[nb] = __builtin_amdgcn_mfma_f32_16x16x32_bf16(kf, qf[kk], accS[nb], 0, 0, 0);
            }

        // softmax: p = exp2(score*SC2 + bias2); packed bf16 pairs
#if USE_1K
        bf16x4 pf[4];
#endif
        #pragma unroll
        for (int nb = 0; nb < 4; nb++) {
            float pr[4];
            #pragma unroll
            for (int r = 0; r < 4; r++)
                pr[r] = __builtin_amdgcn_exp2f(fmaf(accS[nb][r], SC2, bias_r[nb * 4 + r]));
            uint2 w;
            w.x = pk_bf16(pr[0], pr[1]);
            w.y = pk_bf16(pr[2], pr[3]);
#if USE_1K
            union { uint2 u; bf16x4 v; } cv;
            cv.u = w;
            pf[nb] = cv.v;
            // lsum: ones-A MFMA sums pf over k (across quads) -> accL[*][q=col]
            accL = __builtin_amdgcn_mfma_f32_16x16x16bf16_1k(vone, pf[nb], accL, 0, 0, 0);
#else
            #pragma unroll
            for (int r = 0; r < 4; r++) {
                lsum += pr[r];
            }
            const int jp = ((nb * 2 + (quad >> 1)) ^ jsw) * 8 + (quad & 1) * 4;
            *(uint2*)&Ps[wave * 16 + col][jp] = w;
#endif
        }

        // PV
#if USE_1K
        // O^T[d=nb*16+quad*4+r][q=col] += V^T[d][key] * P^T[key][q]
        #pragma unroll
        for (int s = 0; s < 4; s++) {
            #pragma unroll
            for (int nb = 0; nb < 4; nb++) {
                const bf16x4 vf = *(const bf16x4*)
                    &Vs[nb * 16 + col][(((2 * s + (quad >> 1)) ^ jsw) * 8) + (quad & 1) * 4];
                accO[nb] = __builtin_amdgcn_mfma_f32_16x16x16bf16_1k(vf, pf[s], accO[nb], 0, 0, 0);
            }
        }
#else
        #pragma unroll
        for (int kk = 0; kk < 2; kk++) {
            const bf16x8 af = *(const bf16x8*)
                &Ps[wave * 16 + col][((kk * 4 + quad) ^ jsw) * 8];
            #pragma unroll
            for (int nb = 0; nb < 4; nb++) {
                const bf16x8 vf = *(const bf16x8*)
                    &Vs[nb * 16 + col][((kk * 4 + quad) ^ jsw) * 8];
                accO[nb] = __builtin_amdgcn_mfma_f32_16x16x32_bf16(af, vf, accO[nb], 0, 0, 0);
            }
        }
#endif
        pb_lane -= TKB;
    }
    __syncthreads();   // LDS idle before caller reuses arena

#if USE_1K
    // accL rows are all identical = full l for q=col (summed across quads by MFMA)
    const float inv = 1.0f / accL[0];
    const size_t row = (size_t)(b * S_LEN) + qw + col;
    #pragma unroll
    for (int nb = 0; nb < 4; nb++) {
        uint2 w;
        w.x = pk_bf16(accO[nb][0] * inv, accO[nb][1] * inv);
        w.y = pk_bf16(accO[nb][2] * inv, accO[nb][3] * inv);
        *(uint2*)&O[row * D_MODEL + h * HD + nb * 16 + quad * 4] = w;
    }
#else
    lsum += __shfl_xor(lsum, 16);
    lsum += __shfl_xor(lsum, 32);
    #pragma unroll
    for (int r = 0; r < 4; r++) {
        const float inv = 1.0f / __shfl(lsum, quad * 4 + r);
        const size_t row = (size_t)(b * S_LEN) + qw + quad * 4 + r;
        #pragma unroll
        for (int nb = 0; nb < 4; nb++)
            O[row * D_MODEL + h * HD + nb * 16 + col] = f2bf(accO[nb][r] * inv);
    }
#endif
}

// ---------------------------------------------------------------------------
// Phase 3 body: out[4096,1024] = Ab @ Wot^T + bo, fp32 out. 64x128 tile.
// ---------------------------------------------------------------------------
static __device__ __forceinline__ void out_body(
    int bnIdx, int bmIdx, int tid, unsigned char* smem,
    const unsigned short* __restrict__ A, const unsigned short* __restrict__ Bt,
    const float* __restrict__ bias, float* __restrict__ Cout)
{
    const int N = 1024, Kd = 1024;
    unsigned short (*As)[GBK] = (unsigned short(*)[GBK])smem;            // [64][32]
    unsigned short (*Bs)[GBK] = (unsigned short(*)[GBK])(smem + 4096);   // [128][32]

    const int wave = tid >> 6, lane = tid & 63;
    const int quad = lane >> 4, cl = lane & 15;
    const int wm = (wave & 1) * 32, wn = (wave >> 1) * 64;
    const int bm = bmIdx * 64, bn = bnIdx * 128;

    const int ar = tid >> 2, ac = (tid & 3) * 8;
    const unsigned short* aS = A + (size_t)(bm + ar) * Kd + ac;
    const unsigned short* hS0 = Bt + (size_t)(bn + ar) * Kd + ac;
    const unsigned short* hS1 = hS0 + (size_t)64 * Kd;
    unsigned short* aD  = &As[0][0] + wave * 512;
    unsigned short* hD0 = &Bs[0][0] + wave * 512;
    unsigned short* hD1 = hD0 + 2048;

    f32x4 acc[2][4];
    #pragma unroll
    for (int mi = 0; mi < 2; mi++)
        #pragma unroll
        for (int ni = 0; ni < 4; ni++)
            #pragma unroll
            for (int r = 0; r < 4; r++) acc[mi][ni][r] = 0.f;

    for (int k0 = 0; k0 < Kd; k0 += GBK) {
        __syncthreads();
        GLDS(aS, aD);
        GLDS(hS0, hD0); GLDS(hS1, hD1);
        aS += GBK; hS0 += GBK; hS1 += GBK;
        __syncthreads();

        bf16x8 af[2], bh[4];
        #pragma unroll
        for (int mi = 0; mi < 2; mi++)
            af[mi] = *(const bf16x8*)&As[wm + mi * 16 + cl][quad * 8];
        #pragma unroll
        for (int ni = 0; ni < 4; ni++)
            bh[ni] = *(const bf16x8*)&Bs[wn + ni * 16 + cl][quad * 8];
        #pragma unroll
        for (int mi = 0; mi < 2; mi++)
            #pragma unroll
            for (int ni = 0; ni < 4; ni++)
                acc[mi][ni] = __builtin_amdgcn_mfma_f32_16x16x32_bf16(
                    af[mi], bh[ni], acc[mi][ni], 0, 0, 0);
    }

    #pragma unroll
    for (int ni = 0; ni < 4; ni++) {
        const int coln = bn + wn + ni * 16 + cl;
        const float bs = bias[coln];
        #pragma unroll
        for (int mi = 0; mi < 2; mi++) {
            const int row0 = bm + wm + mi * 16 + quad * 4;
            #pragma unroll
            for (int r = 0; r < 4; r++)
                Cout[(size_t)(row0 + r) * N + coln] = acc[mi][ni][r] + bs;
        }
    }
}

// ---------------------------------------------------------------------------
// Persistent cooperative kernel: all 4 phases, grid = 1024 blocks (4/CU).
// ---------------------------------------------------------------------------
__global__ __launch_bounds__(256, 4) void fused_all(
    const float* x, const float* Wq, const float* Wk, const float* Wv,
    const float* Wo, const float* pos_bias, const float* bq, const float* bv,
    const float* bo, unsigned short* xb, unsigned short* Wqkvt,
    unsigned short* Wot, unsigned short* QKV, unsigned short* Ab,
    float* pb_t, float* out)
{
    cg::grid_group grid = cg::this_grid();
    __shared__ __align__(16) unsigned char smem[ARENA_BYTES];
    const int tid = threadIdx.x;
    const int nb = gridDim.x;   // 1024

    // phase 0: prep (6208 vblocks)
    for (int vb = blockIdx.x; vb < 6208; vb += nb)
        prep_body(vb, tid, smem, x, Wq, Wk, Wv, Wo, pos_bias, xb, Wqkvt, Wot, pb_t);
    grid.sync();

    // phase 1: QKV GEMM (768 tiles: 24 x 32)
    if ((int)blockIdx.x < 768)
        qkv_body(blockIdx.x % 24, blockIdx.x / 24, tid, smem, xb, Wqkvt, bq, bv, QKV);
    grid.sync();

    // phase 2: attention (1024 tiles: 32 x 16 x 2)
    {
        const int vb = blockIdx.x;
        attn_body(vb & 31, (vb >> 5) & 15, vb >> 9, tid, smem,
                  QKV, QKV + (size_t)4 * 1024 * 1024,
                  QKV + (size_t)8 * 1024 * 1024, pb_t, Ab);
    }
    grid.sync();

    // phase 3: out projection (512 tiles: 8 x 64)
    if ((int)blockIdx.x < 512)
        out_body(blockIdx.x % 8, blockIdx.x / 8, tid, smem, Ab, Wot, bo, out);
}

// ---------------------------------------------------------------------------
// Fallback standalone kernels (identical bodies, 4 separate launches).
// ---------------------------------------------------------------------------
__global__ __launch_bounds__(256) void prep_k(
    const float* x, const float* Wq, const float* Wk, const float* Wv,
    const float* Wo, const float* pos_bias, unsigned short* xb,
    unsigned short* Wqkvt, unsigned short* Wot, float* pb_t)
{
    __shared__ __align__(16) unsigned char smem[4224];
    prep_body(blockIdx.x, threadIdx.x, smem, x, Wq, Wk, Wv, Wo, pos_bias,
              xb, Wqkvt, Wot, pb_t);
}

__global__ __launch_bounds__(256) void qkv_k(
    const unsigned short* A, const unsigned short* Bt,
    const float* bq, const float* bv, unsigned short* Cout)
{
    __shared__ __align__(16) unsigned char smem[16384];
    qkv_body(blockIdx.x, blockIdx.y, threadIdx.x, smem, A, Bt, bq, bv, Cout);
}

__global__ __launch_bounds__(256) void attn_k(
    const unsigned short* Q, const unsigned short* K,
    const unsigned short* VT, const float* pb_t, unsigned short* O)
{
    __shared__ __align__(16) unsigned char smem[ARENA_BYTES];
    attn_body(blockIdx.x, blockIdx.y, blockIdx.z, threadIdx.x, smem,
              Q, K, VT, pb_t, O);
}

__global__ __launch_bounds__(256) void out_k(
    const unsigned short* A, const unsigned short* Bt,
    const float* bias, float* Cout)
{
    __shared__ __align__(16) unsigned char smem[12288];
    out_body(blockIdx.x, blockIdx.y, threadIdx.x, smem, A, Bt, bias, Cout);
}

// ---------------------------------------------------------------------------
extern "C" void kernel_launch(void* const* d_in, const int* in_sizes, int n_in,
                              void* d_out, int out_size, void* d_ws, size_t ws_size,
                              hipStream_t stream)
{
    const float* x        = (const float*)d_in[0];
    const float* Wq       = (const float*)d_in[1];
    const float* bq       = (const float*)d_in[2];
    const float* Wk       = (const float*)d_in[3];
    const float* Wv       = (const float*)d_in[4];
    const float* bv       = (const float*)d_in[5];
    const float* Wo       = (const float*)d_in[6];
    const float* bo       = (const float*)d_in[7];
    const float* pos_bias = (const float*)d_in[8];
    float* out = (float*)d_out;

    const size_t ELEMS  = (size_t)BATCH * S_LEN * D_MODEL;  // 4 Mi
    const size_t WELEMS = (size_t)D_MODEL * D_MODEL;        // 1 Mi
    unsigned short* xb     = (unsigned short*)d_ws;
    unsigned short* Wqkvt  = xb + ELEMS;                    // [3072][1024]
    unsigned short* Wot    = Wqkvt + 3 * WELEMS;
    unsigned short* QKV    = Wot + WELEMS;                  // Qb | Kb | VTb
    unsigned short* Ab     = QKV + 3 * ELEMS;               // attn out bf16 [B,S,D]
    float* pb_t            = (float*)(Ab + ELEMS);          // [NH][4096]

    void* args[] = {
        (void*)&x, (void*)&Wq, (void*)&Wk, (void*)&Wv, (void*)&Wo,
        (void*)&pos_bias, (void*)&bq, (void*)&bv, (void*)&bo,
        (void*)&xb, (void*)&Wqkvt, (void*)&Wot, (void*)&QKV, (void*)&Ab,
        (void*)&pb_t, (void*)&out,
    };
    hipError_t err = hipLaunchCooperativeKernel(
        (const void*)fused_all, dim3(1024), dim3(256), args, 0, stream);

    if (err != hipSuccess) {
        // deterministic fallback: identical 4-launch pipeline
        prep_k<<<6208, 256, 0, stream>>>(x, Wq, Wk, Wv, Wo, pos_bias,
                                         xb, Wqkvt, Wot, pb_t);
        qkv_k<<<dim3(24, 32), 256, 0, stream>>>(xb, Wqkvt, bq, bv, QKV);
        attn_k<<<dim3(32, 16, 2), 256, 0, stream>>>(
            QKV, QKV + 4 * ELEMS / 4, QKV + 2 * ELEMS, pb_t, Ab);
        out_k<<<dim3(8, 64), 256, 0, stream>>>(Ab, Wot, bo, out);
    }
}